// Round 11
// baseline (47.959 us; speedup 1.0000x reference)
//
#include <hip/hip_runtime.h>
#include <math.h>

#define GEO_N 256

// Single-instruction HW approximations (~1 ulp) — validated r9/r10 (absmax 0.0).
__device__ __forceinline__ float frcp(float x) { return __builtin_amdgcn_rcpf(x); }
__device__ __forceinline__ float frsq(float x) { return __builtin_amdgcn_rsqf(x); }
__device__ __forceinline__ float fsqrtf_(float x) { return __builtin_amdgcn_sqrtf(x); }

__device__ __forceinline__ float wredf(float v) {
#pragma unroll
  for (int off = 32; off; off >>= 1) v += __shfl_xor(v, off, 64);
  return v;
}

// Branchless fast Jacobi rotation (both sides) + accumulate into V. r9-validated.
template <int P, int Q>
__device__ __forceinline__ void jrot(float G[3][3], float V[3][3]) {
  const float apq = G[P][Q];
  const float tau = (G[Q][Q] - G[P][P]) * 0.5f * frcp(apq);
  const float tt = fsqrtf_(1.0f + tau * tau);
  const float tr = frcp(tau + copysignf(tt, tau));
  const float cr = frsq(1.0f + tr * tr);
  const bool skip = fabsf(apq) < 1e-30f;
  const float c = skip ? 1.0f : cr;
  const float s = skip ? 0.0f : tr * cr;
#pragma unroll
  for (int k = 0; k < 3; ++k) {
    float gkp = G[k][P], gkq = G[k][Q];
    G[k][P] = c * gkp - s * gkq;
    G[k][Q] = s * gkp + c * gkq;
  }
#pragma unroll
  for (int k = 0; k < 3; ++k) {
    float gpk = G[P][k], gqk = G[Q][k];
    G[P][k] = c * gpk - s * gqk;
    G[Q][k] = s * gpk + c * gqk;
  }
#pragma unroll
  for (int k = 0; k < 3; ++k) {
    float vkp = V[k][P], vkq = V[k][Q];
    V[k][P] = c * vkp - s * vkq;
    V[k][Q] = s * vkp + c * vkq;
  }
}

// From 16 raw moment sums -> R(9), scale, T(3) in bc[0..12]. r9-validated.
__device__ __forceinline__ void solve_rst(const float s0[16], float bc[13]) {
  const float invN = 1.0f / (float)GEO_N;
  const float smx = s0[0] * invN, smy = s0[1] * invN, smz = s0[2] * invN;
  const float dmx = s0[3] * invN, dmy = s0[4] * invN, dmz = s0[5] * invN;
  float A[3][3];
  A[0][0] = s0[6] * invN - dmx * smx;  A[0][1] = s0[7] * invN - dmx * smy;  A[0][2] = s0[8] * invN - dmx * smz;
  A[1][0] = s0[9] * invN - dmy * smx;  A[1][1] = s0[10] * invN - dmy * smy; A[1][2] = s0[11] * invN - dmy * smz;
  A[2][0] = s0[12] * invN - dmz * smx; A[2][1] = s0[13] * invN - dmz * smy; A[2][2] = s0[14] * invN - dmz * smz;
  const float var_sum = s0[15] * invN - (smx * smx + smy * smy + smz * smz);

  float G[3][3];
#pragma unroll
  for (int i = 0; i < 3; ++i)
#pragma unroll
    for (int j = 0; j < 3; ++j)
      G[i][j] = A[0][i] * A[0][j] + A[1][i] * A[1][j] + A[2][i] * A[2][j];
  float V[3][3] = {{1, 0, 0}, {0, 1, 0}, {0, 0, 1}};
#pragma unroll
  for (int sweep = 0; sweep < 4; ++sweep) {
    jrot<0, 1>(G, V);
    jrot<0, 2>(G, V);
    jrot<1, 2>(G, V);
  }
  float l0 = G[0][0], l1 = G[1][1], l2 = G[2][2];
  if (l0 < l1) { float tl = l0; l0 = l1; l1 = tl;
#pragma unroll
    for (int k = 0; k < 3; ++k) { float tv = V[k][0]; V[k][0] = V[k][1]; V[k][1] = tv; } }
  if (l0 < l2) { float tl = l0; l0 = l2; l2 = tl;
#pragma unroll
    for (int k = 0; k < 3; ++k) { float tv = V[k][0]; V[k][0] = V[k][2]; V[k][2] = tv; } }
  if (l1 < l2) { float tl = l1; l1 = l2; l2 = tl;
#pragma unroll
    for (int k = 0; k < 3; ++k) { float tv = V[k][1]; V[k][1] = V[k][2]; V[k][2] = tv; } }
  const float sig0 = fsqrtf_(fmaxf(l0, 0.0f));
  const float sig1 = fsqrtf_(fmaxf(l1, 0.0f));
  const float sig2 = fsqrtf_(fmaxf(l2, 0.0f));

  float v0[3] = {V[0][0], V[1][0], V[2][0]};
  float v1[3] = {V[0][1], V[1][1], V[2][1]};
  float v2[3] = {V[0][2], V[1][2], V[2][2]};
  float u0[3], u1[3], u2r[3];
#pragma unroll
  for (int i = 0; i < 3; ++i) {
    u0[i]  = A[i][0] * v0[0] + A[i][1] * v0[1] + A[i][2] * v0[2];
    u1[i]  = A[i][0] * v1[0] + A[i][1] * v1[1] + A[i][2] * v1[2];
    u2r[i] = A[i][0] * v2[0] + A[i][1] * v2[1] + A[i][2] * v2[2];
  }
  float n0 = u0[0] * u0[0] + u0[1] * u0[1] + u0[2] * u0[2];
  if (n0 > 1e-28f) { float inv = frsq(n0); u0[0] *= inv; u0[1] *= inv; u0[2] *= inv; }
  else { u0[0] = 1.0f; u0[1] = 0.0f; u0[2] = 0.0f; }
  float d01 = u1[0] * u0[0] + u1[1] * u0[1] + u1[2] * u0[2];
  u1[0] -= d01 * u0[0]; u1[1] -= d01 * u0[1]; u1[2] -= d01 * u0[2];
  float n1 = u1[0] * u1[0] + u1[1] * u1[1] + u1[2] * u1[2];
  if (n1 > 1e-28f) { float inv = frsq(n1); u1[0] *= inv; u1[1] *= inv; u1[2] *= inv; }
  else {
    float ex[3] = {1, 0, 0}, ey[3] = {0, 1, 0};
    const float* e = (fabsf(u0[0]) < 0.9f) ? ex : ey;
    u1[0] = u0[1] * e[2] - u0[2] * e[1];
    u1[1] = u0[2] * e[0] - u0[0] * e[2];
    u1[2] = u0[0] * e[1] - u0[1] * e[0];
    float nn = u1[0] * u1[0] + u1[1] * u1[1] + u1[2] * u1[2];
    float inv = frsq(nn);
    u1[0] *= inv; u1[1] *= inv; u1[2] *= inv;
  }
  float u2[3] = {u0[1] * u1[2] - u0[2] * u1[1],
                 u0[2] * u1[0] - u0[0] * u1[2],
                 u0[0] * u1[1] - u0[1] * u1[0]};
  float d2 = u2[0] * u2r[0] + u2[1] * u2r[1] + u2[2] * u2r[2];
  if (d2 < 0.0f) { u2[0] = -u2[0]; u2[1] = -u2[1]; u2[2] = -u2[2]; }

  const float scale = (sig0 + sig1 + sig2) * frcp(fmaxf(var_sum, 1e-30f));
  float R[3][3];
#pragma unroll
  for (int i = 0; i < 3; ++i)
#pragma unroll
    for (int j = 0; j < 3; ++j)
      R[i][j] = u0[i] * v0[j] + u1[i] * v1[j] + u2[i] * v2[j];
  const float Tx = dmx - scale * (R[0][0] * smx + R[0][1] * smy + R[0][2] * smz);
  const float Ty = dmy - scale * (R[1][0] * smx + R[1][1] * smy + R[1][2] * smz);
  const float Tz = dmz - scale * (R[2][0] * smx + R[2][1] * smy + R[2][2] * smz);
#pragma unroll
  for (int i = 0; i < 3; ++i)
#pragma unroll
    for (int j = 0; j < 3; ++j) bc[3 * i + j] = R[i][j];
  bc[9] = scale; bc[10] = Tx; bc[11] = Ty; bc[12] = Tz;
}

// ---------- Single-pass, barrier-free, COALESCED: one WAVE = 2 batches. ----------
// Stage 12 x 1KB contiguous chunks (lane L reads float4 L of each chunk ->
// perfect coalescing) into the wave's private 12KB LDS slice via reg-staged
// ds_write (wave-private -> no barriers, compiler orders ds_write->ds_read).
// Lane l: group g=l>>5 (batch), q=l&31 owns points [q*8, q*8+8) read back as
// whole points from LDS. Then: 17-shfl group butterfly -> 16-shfl gather ->
// per-lane solve (each lane has its own batch's params) -> zero-shuffle error
// from registers -> wredf.
__global__ __launch_bounds__(256) void geo_wave2c(const float* __restrict__ kp,
                                                  const int* __restrict__ perm,
                                                  float* __restrict__ partials,
                                                  int B, int NW) {
  __shared__ float4 lds4[3072];  // 48KB = 4 waves x 12KB (wave-private slices)
  const int tid = threadIdx.x;
  const int w = tid >> 6, lane = tid & 63;
  const int wid = blockIdx.x * 4 + w;
  if (wid >= NW) return;  // no barriers anywhere -> early return safe
  const int g = lane >> 5, q = lane & 31;
  const int b0 = wid * 2;
  float4* wbuf = lds4 + w * 768;  // this wave's 12KB
  const float4* base = (const float4*)kp;

  const int pm0 = perm[min(b0, B - 1)];
  const int pm1 = perm[min(b0 + 1, B - 1)];
  const int bs0 = min(b0, B - 1), bs1 = min(b0 + 1, B - 1);

  // ---- Stage: 12 perfectly-coalesced 1KB loads -> regs -> LDS ----
  float4 st[12];
#pragma unroll
  for (int c = 0; c < 3; ++c) {
    st[c]     = base[(size_t)bs0 * 192 + c * 64 + lane];  // batch0 src
    st[3 + c] = base[(size_t)pm0 * 192 + c * 64 + lane];  // batch0 dst
    st[6 + c] = base[(size_t)bs1 * 192 + c * 64 + lane];  // batch1 src
    st[9 + c] = base[(size_t)pm1 * 192 + c * 64 + lane];  // batch1 dst
  }
#pragma unroll
  for (int c = 0; c < 3; ++c) {
    wbuf[      c * 64 + lane] = st[c];       // [g=0][s=0]
    wbuf[192 + c * 64 + lane] = st[3 + c];   // [g=0][s=1]
    wbuf[384 + c * 64 + lane] = st[6 + c];   // [g=1][s=0]
    wbuf[576 + c * 64 + lane] = st[9 + c];   // [g=1][s=1]
  }

  // ---- Read back own 8 whole points per side (6+6 ds_read_b128) ----
  float4 SP[6], DP[6];
#pragma unroll
  for (int j = 0; j < 6; ++j) {
    SP[j] = wbuf[g * 384 +       q * 6 + j];
    DP[j] = wbuf[g * 384 + 192 + q * 6 + j];
  }
  float s[24], d[24];
#pragma unroll
  for (int j = 0; j < 6; ++j) {
    s[4 * j + 0] = SP[j].x; s[4 * j + 1] = SP[j].y; s[4 * j + 2] = SP[j].z; s[4 * j + 3] = SP[j].w;
    d[4 * j + 0] = DP[j].x; d[4 * j + 1] = DP[j].y; d[4 * j + 2] = DP[j].z; d[4 * j + 3] = DP[j].w;
  }

  // ---- Per-lane partial moments over 8 points ----
  float r[16];
#pragma unroll
  for (int k = 0; k < 16; ++k) r[k] = 0.0f;
#pragma unroll
  for (int p = 0; p < 8; ++p) {
    const float sx = s[3 * p + 0], sy = s[3 * p + 1], sz = s[3 * p + 2];
    const float dx = d[3 * p + 0], dy = d[3 * p + 1], dz = d[3 * p + 2];
    r[0] += sx; r[1] += sy; r[2] += sz;
    r[3] += dx; r[4] += dy; r[5] += dz;
    r[6] += dx * sx; r[7] += dx * sy; r[8] += dx * sz;
    r[9] += dy * sx; r[10] += dy * sy; r[11] += dy * sz;
    r[12] += dz * sx; r[13] += dz * sy; r[14] += dz * sz;
    r[15] += sx * sx + sy * sy + sz * sz;
  }

  // ---- Reduce within the 32-lane group: 4-stage halving (xor 1,2,4,8)
  // leaves lane holding moment bitrev4(q&15) over its 16-half; xor16 merges
  // the halves. Construction identical to r6-r10-validated hred16.
  const int b1 = q & 1, b2 = (q >> 1) & 1, b3 = (q >> 2) & 1, b4 = (q >> 3) & 1;
  float v8[8], v4[4], v2[2], v1;
#pragma unroll
  for (int k = 0; k < 8; ++k) {
    float send = b1 ? r[k] : r[k + 8];
    float recv = __shfl_xor(send, 1, 64);
    v8[k] = (b1 ? r[k + 8] : r[k]) + recv;
  }
#pragma unroll
  for (int k = 0; k < 4; ++k) {
    float send = b2 ? v8[k] : v8[k + 4];
    float recv = __shfl_xor(send, 2, 64);
    v4[k] = (b2 ? v8[k + 4] : v8[k]) + recv;
  }
#pragma unroll
  for (int k = 0; k < 2; ++k) {
    float send = b3 ? v4[k] : v4[k + 2];
    float recv = __shfl_xor(send, 4, 64);
    v2[k] = (b3 ? v4[k + 2] : v4[k]) + recv;
  }
  {
    float send = b4 ? v2[0] : v2[1];
    float recv = __shfl_xor(send, 8, 64);
    v1 = (b4 ? v2[1] : v2[0]) + recv;
  }
  const float parked = v1 + __shfl_xor(v1, 16, 64);  // full 32-lane-group sum

  // ---- Gather own batch's 16 moments (16 shfl within the group) ----
  // Moment k of group g sits at lane (g<<5) | bitrev4(k) (both 16-halves).
  constexpr int br[16] = {0, 8, 4, 12, 2, 10, 6, 14, 1, 9, 5, 13, 3, 11, 7, 15};
  float s0[16];
#pragma unroll
  for (int k = 0; k < 16; ++k)
    s0[k] = __shfl(parked, (lane & 0x20) | br[k], 64);

  // ---- Solve: each lane solves its own batch (one issue cost per wave) ----
  float bc[13];
  solve_rst(s0, bc);

  // ---- Error: own params on own registers — zero shuffles ----
  float acc = 0.0f;
#pragma unroll
  for (int p = 0; p < 8; ++p) {
    const float sx = s[3 * p + 0], sy = s[3 * p + 1], sz = s[3 * p + 2];
    const float dx = d[3 * p + 0], dy = d[3 * p + 1], dz = d[3 * p + 2];
    const float e0 = bc[9] * (bc[0] * sx + bc[1] * sy + bc[2] * sz) + bc[10] - dx;
    const float e1 = bc[9] * (bc[3] * sx + bc[4] * sy + bc[5] * sz) + bc[11] - dy;
    const float e2 = bc[9] * (bc[6] * sx + bc[7] * sy + bc[8] * sz) + bc[12] - dz;
    acc += fabsf(e0) + fabsf(e1) + fabsf(e2);
  }
  if (b0 + g >= B) acc = 0.0f;  // tail safety (B%2==0 here -> never taken)

  acc = wredf(acc);
  if (lane == 0) partials[wid] = acc;
}

// ---------- Final reduce ----------
__global__ __launch_bounds__(1024) void geo_fin(const float* __restrict__ partials,
                                                float* __restrict__ out, int n,
                                                double inv_total) {
  const int t = threadIdx.x;
  double acc = 0.0;
  for (int i = t; i < n; i += 1024) acc += (double)partials[i];
#pragma unroll
  for (int off = 32; off; off >>= 1) acc += __shfl_xor(acc, off, 64);
  __shared__ double sred[16];
  if ((t & 63) == 0) sred[t >> 6] = acc;
  __syncthreads();
  if (t == 0) {
    double tot = 0.0;
#pragma unroll
    for (int k = 0; k < 16; ++k) tot += sred[k];
    out[0] = (float)(tot * inv_total);
  }
}

extern "C" void kernel_launch(void* const* d_in, const int* in_sizes, int n_in,
                              void* d_out, int out_size, void* d_ws, size_t ws_size,
                              hipStream_t stream) {
  const float* kp = (const float*)d_in[0];
  const int* perm = (const int*)d_in[1];
  float* out = (float*)d_out;
  const int B = in_sizes[1];
  const double inv_total = 1.0 / ((double)B * (double)GEO_N * 3.0);

  const int NW = (B + 1) / 2;      // one wave per 2 batches
  float* partials = (float*)d_ws;  // NW floats
  const int grid = (NW + 3) / 4;   // 4 waves per 256-thread block
  geo_wave2c<<<grid, 256, 0, stream>>>(kp, perm, partials, B, NW);
  geo_fin<<<1, 1024, 0, stream>>>(partials, out, NW, inv_total);
}

// Round 12
// 43.443 us; speedup vs baseline: 1.1039x; 1.1039x over previous
//
#include <hip/hip_runtime.h>
#include <math.h>

#define GEO_N 256

// Single-instruction HW approximations (~1 ulp) — validated r9-r11 (absmax 0.0).
__device__ __forceinline__ float frcp(float x) { return __builtin_amdgcn_rcpf(x); }
__device__ __forceinline__ float frsq(float x) { return __builtin_amdgcn_rsqf(x); }
__device__ __forceinline__ float fsqrtf_(float x) { return __builtin_amdgcn_sqrtf(x); }

__device__ __forceinline__ float wredf(float v) {
#pragma unroll
  for (int off = 32; off; off >>= 1) v += __shfl_xor(v, off, 64);
  return v;
}

// Branchless fast Jacobi rotation (both sides) + accumulate into V. r9-validated.
template <int P, int Q>
__device__ __forceinline__ void jrot(float G[3][3], float V[3][3]) {
  const float apq = G[P][Q];
  const float tau = (G[Q][Q] - G[P][P]) * 0.5f * frcp(apq);
  const float tt = fsqrtf_(1.0f + tau * tau);
  const float tr = frcp(tau + copysignf(tt, tau));
  const float cr = frsq(1.0f + tr * tr);
  const bool skip = fabsf(apq) < 1e-30f;
  const float c = skip ? 1.0f : cr;
  const float s = skip ? 0.0f : tr * cr;
#pragma unroll
  for (int k = 0; k < 3; ++k) {
    float gkp = G[k][P], gkq = G[k][Q];
    G[k][P] = c * gkp - s * gkq;
    G[k][Q] = s * gkp + c * gkq;
  }
#pragma unroll
  for (int k = 0; k < 3; ++k) {
    float gpk = G[P][k], gqk = G[Q][k];
    G[P][k] = c * gpk - s * gqk;
    G[Q][k] = s * gpk + c * gqk;
  }
#pragma unroll
  for (int k = 0; k < 3; ++k) {
    float vkp = V[k][P], vkq = V[k][Q];
    V[k][P] = c * vkp - s * vkq;
    V[k][Q] = s * vkp + c * vkq;
  }
}

// From 16 raw moment sums -> R(9), scale, T(3) in bc[0..12]. r9-validated.
__device__ __forceinline__ void solve_rst(const float s0[16], float bc[13]) {
  const float invN = 1.0f / (float)GEO_N;
  const float smx = s0[0] * invN, smy = s0[1] * invN, smz = s0[2] * invN;
  const float dmx = s0[3] * invN, dmy = s0[4] * invN, dmz = s0[5] * invN;
  float A[3][3];
  A[0][0] = s0[6] * invN - dmx * smx;  A[0][1] = s0[7] * invN - dmx * smy;  A[0][2] = s0[8] * invN - dmx * smz;
  A[1][0] = s0[9] * invN - dmy * smx;  A[1][1] = s0[10] * invN - dmy * smy; A[1][2] = s0[11] * invN - dmy * smz;
  A[2][0] = s0[12] * invN - dmz * smx; A[2][1] = s0[13] * invN - dmz * smy; A[2][2] = s0[14] * invN - dmz * smz;
  const float var_sum = s0[15] * invN - (smx * smx + smy * smy + smz * smz);

  float G[3][3];
#pragma unroll
  for (int i = 0; i < 3; ++i)
#pragma unroll
    for (int j = 0; j < 3; ++j)
      G[i][j] = A[0][i] * A[0][j] + A[1][i] * A[1][j] + A[2][i] * A[2][j];
  float V[3][3] = {{1, 0, 0}, {0, 1, 0}, {0, 0, 1}};
#pragma unroll
  for (int sweep = 0; sweep < 4; ++sweep) {
    jrot<0, 1>(G, V);
    jrot<0, 2>(G, V);
    jrot<1, 2>(G, V);
  }
  float l0 = G[0][0], l1 = G[1][1], l2 = G[2][2];
  if (l0 < l1) { float tl = l0; l0 = l1; l1 = tl;
#pragma unroll
    for (int k = 0; k < 3; ++k) { float tv = V[k][0]; V[k][0] = V[k][1]; V[k][1] = tv; } }
  if (l0 < l2) { float tl = l0; l0 = l2; l2 = tl;
#pragma unroll
    for (int k = 0; k < 3; ++k) { float tv = V[k][0]; V[k][0] = V[k][2]; V[k][2] = tv; } }
  if (l1 < l2) { float tl = l1; l1 = l2; l2 = tl;
#pragma unroll
    for (int k = 0; k < 3; ++k) { float tv = V[k][1]; V[k][1] = V[k][2]; V[k][2] = tv; } }
  const float sig0 = fsqrtf_(fmaxf(l0, 0.0f));
  const float sig1 = fsqrtf_(fmaxf(l1, 0.0f));
  const float sig2 = fsqrtf_(fmaxf(l2, 0.0f));

  float v0[3] = {V[0][0], V[1][0], V[2][0]};
  float v1[3] = {V[0][1], V[1][1], V[2][1]};
  float v2[3] = {V[0][2], V[1][2], V[2][2]};
  float u0[3], u1[3], u2r[3];
#pragma unroll
  for (int i = 0; i < 3; ++i) {
    u0[i]  = A[i][0] * v0[0] + A[i][1] * v0[1] + A[i][2] * v0[2];
    u1[i]  = A[i][0] * v1[0] + A[i][1] * v1[1] + A[i][2] * v1[2];
    u2r[i] = A[i][0] * v2[0] + A[i][1] * v2[1] + A[i][2] * v2[2];
  }
  float n0 = u0[0] * u0[0] + u0[1] * u0[1] + u0[2] * u0[2];
  if (n0 > 1e-28f) { float inv = frsq(n0); u0[0] *= inv; u0[1] *= inv; u0[2] *= inv; }
  else { u0[0] = 1.0f; u0[1] = 0.0f; u0[2] = 0.0f; }
  float d01 = u1[0] * u0[0] + u1[1] * u0[1] + u1[2] * u0[2];
  u1[0] -= d01 * u0[0]; u1[1] -= d01 * u0[1]; u1[2] -= d01 * u0[2];
  float n1 = u1[0] * u1[0] + u1[1] * u1[1] + u1[2] * u1[2];
  if (n1 > 1e-28f) { float inv = frsq(n1); u1[0] *= inv; u1[1] *= inv; u1[2] *= inv; }
  else {
    float ex[3] = {1, 0, 0}, ey[3] = {0, 1, 0};
    const float* e = (fabsf(u0[0]) < 0.9f) ? ex : ey;
    u1[0] = u0[1] * e[2] - u0[2] * e[1];
    u1[1] = u0[2] * e[0] - u0[0] * e[2];
    u1[2] = u0[0] * e[1] - u0[1] * e[0];
    float nn = u1[0] * u1[0] + u1[1] * u1[1] + u1[2] * u1[2];
    float inv = frsq(nn);
    u1[0] *= inv; u1[1] *= inv; u1[2] *= inv;
  }
  float u2[3] = {u0[1] * u1[2] - u0[2] * u1[1],
                 u0[2] * u1[0] - u0[0] * u1[2],
                 u0[0] * u1[1] - u0[1] * u1[0]};
  float d2 = u2[0] * u2r[0] + u2[1] * u2r[1] + u2[2] * u2r[2];
  if (d2 < 0.0f) { u2[0] = -u2[0]; u2[1] = -u2[1]; u2[2] = -u2[2]; }

  const float scale = (sig0 + sig1 + sig2) * frcp(fmaxf(var_sum, 1e-30f));
  float R[3][3];
#pragma unroll
  for (int i = 0; i < 3; ++i)
#pragma unroll
    for (int j = 0; j < 3; ++j)
      R[i][j] = u0[i] * v0[j] + u1[i] * v1[j] + u2[i] * v2[j];
  const float Tx = dmx - scale * (R[0][0] * smx + R[0][1] * smy + R[0][2] * smz);
  const float Ty = dmy - scale * (R[1][0] * smx + R[1][1] * smy + R[1][2] * smz);
  const float Tz = dmz - scale * (R[2][0] * smx + R[2][1] * smy + R[2][2] * smz);
#pragma unroll
  for (int i = 0; i < 3; ++i)
#pragma unroll
    for (int j = 0; j < 3; ++j) bc[3 * i + j] = R[i][j];
  bc[9] = scale; bc[10] = Tx; bc[11] = Ty; bc[12] = Tz;
}

// ---------- r9 structure + interleaved (de-phase-locked) load schedule. ----------
// One WAVE = 4 batches, all points register-resident, barrier-free. The ONLY
// change vs r9: loads are issued in segments interleaved with per-batch moment
// computation, fenced by sched_barrier(0) so the compiler cannot re-hoist the
// whole 24-load burst to the top. Schedule: [L0,L1][C0,L2][C1,L3][C2][C3...].
__global__ __launch_bounds__(256) void geo_wave4p(const float* __restrict__ kp,
                                                  const int* __restrict__ perm,
                                                  float* __restrict__ partials,
                                                  int B, int NW) {
  const int wid = (blockIdx.x << 2) | (threadIdx.x >> 6);
  if (wid >= NW) return;  // no barriers in this kernel -> early return safe
  const int lane = threadIdx.x & 63;
  const int b0 = wid * 4;
  const float4* base = (const float4*)kp;

  int pm[4];
#pragma unroll
  for (int i = 0; i < 4; ++i) pm[i] = perm[min(b0 + i, B - 1)];

  float4 S[4][3], D[4][3];
  float parked = 0.0f;

#define GEO_LOAD(i)                                                        \
  {                                                                        \
    const int bb = min(b0 + (i), B - 1);                                   \
    const float4* s4 = base + (size_t)bb * 192 + lane * 3;                 \
    const float4* d4 = base + (size_t)pm[(i)] * 192 + lane * 3;            \
    S[(i)][0] = s4[0]; S[(i)][1] = s4[1]; S[(i)][2] = s4[2];               \
    D[(i)][0] = d4[0]; D[(i)][1] = d4[1]; D[(i)][2] = d4[2];               \
  }

#define GEO_MOM(i)                                                         \
  {                                                                        \
    const float s_[12] = {S[(i)][0].x, S[(i)][0].y, S[(i)][0].z, S[(i)][0].w, \
                          S[(i)][1].x, S[(i)][1].y, S[(i)][1].z, S[(i)][1].w, \
                          S[(i)][2].x, S[(i)][2].y, S[(i)][2].z, S[(i)][2].w}; \
    const float d_[12] = {D[(i)][0].x, D[(i)][0].y, D[(i)][0].z, D[(i)][0].w, \
                          D[(i)][1].x, D[(i)][1].y, D[(i)][1].z, D[(i)][1].w, \
                          D[(i)][2].x, D[(i)][2].y, D[(i)][2].z, D[(i)][2].w}; \
    float r[16];                                                           \
    _Pragma("unroll") for (int k = 0; k < 16; ++k) r[k] = 0.0f;            \
    _Pragma("unroll") for (int p = 0; p < 4; ++p) {                        \
      const float sx = s_[3 * p + 0], sy = s_[3 * p + 1], sz = s_[3 * p + 2]; \
      const float dx = d_[3 * p + 0], dy = d_[3 * p + 1], dz = d_[3 * p + 2]; \
      r[0] += sx; r[1] += sy; r[2] += sz;                                  \
      r[3] += dx; r[4] += dy; r[5] += dz;                                  \
      r[6] += dx * sx; r[7] += dx * sy; r[8] += dx * sz;                   \
      r[9] += dy * sx; r[10] += dy * sy; r[11] += dy * sz;                 \
      r[12] += dz * sx; r[13] += dz * sy; r[14] += dz * sz;                \
      r[15] += sx * sx + sy * sy + sz * sz;                                \
    }                                                                      \
    /* hred16 (r6-r11 validated): lane j ends with moment bitrev4(j&15) */ \
    const int b1 = lane & 1, b2 = (lane >> 1) & 1, b3 = (lane >> 2) & 1, b4 = (lane >> 3) & 1; \
    float v8[8], v4_[4], v2[2], v1;                                        \
    _Pragma("unroll") for (int k = 0; k < 8; ++k) {                        \
      float send = b1 ? r[k] : r[k + 8];                                   \
      float recv = __shfl_xor(send, 1, 64);                                \
      v8[k] = (b1 ? r[k + 8] : r[k]) + recv;                               \
    }                                                                      \
    _Pragma("unroll") for (int k = 0; k < 4; ++k) {                        \
      float send = b2 ? v8[k] : v8[k + 4];                                 \
      float recv = __shfl_xor(send, 2, 64);                                \
      v4_[k] = (b2 ? v8[k + 4] : v8[k]) + recv;                            \
    }                                                                      \
    _Pragma("unroll") for (int k = 0; k < 2; ++k) {                        \
      float send = b3 ? v4_[k] : v4_[k + 2];                               \
      float recv = __shfl_xor(send, 4, 64);                                \
      v2[k] = (b3 ? v4_[k + 2] : v4_[k]) + recv;                           \
    }                                                                      \
    {                                                                      \
      float send = b4 ? v2[0] : v2[1];                                     \
      float recv = __shfl_xor(send, 8, 64);                                \
      v1 = (b4 ? v2[1] : v2[0]) + recv;                                    \
    }                                                                      \
    v1 += __shfl_xor(v1, 16, 64);                                          \
    v1 += __shfl_xor(v1, 32, 64);                                          \
    if ((lane >> 4) == (i)) parked = v1;                                   \
  }

  // ---- Pipelined schedule: loads interleaved with compute ----
  GEO_LOAD(0)
  GEO_LOAD(1)
  __builtin_amdgcn_sched_barrier(0);
  GEO_MOM(0)
  GEO_LOAD(2)
  __builtin_amdgcn_sched_barrier(0);
  GEO_MOM(1)
  GEO_LOAD(3)
  __builtin_amdgcn_sched_barrier(0);
  GEO_MOM(2)
  __builtin_amdgcn_sched_barrier(0);
  GEO_MOM(3)

#undef GEO_LOAD
#undef GEO_MOM

  // ---- shfl-transpose: lane t gathers batch (t&3)'s 16 moments (r8/r9) ----
  constexpr int br[16] = {0, 8, 4, 12, 2, 10, 6, 14, 1, 9, 5, 13, 3, 11, 7, 15};
  float s0[16];
#pragma unroll
  for (int k = 0; k < 16; ++k)
    s0[k] = __shfl(parked, ((lane & 3) << 4) | br[k], 64);

  // ---- One solve per wave (lane t solves batch b0 + (t&3)) ----
  float bc[13];
  solve_rst(s0, bc);

  // ---- Errors from live registers; params broadcast from lane i ----
  float acc = 0.0f;
#pragma unroll
  for (int i = 0; i < 4; ++i) {
    const float R00 = __shfl(bc[0], i, 64), R01 = __shfl(bc[1], i, 64), R02 = __shfl(bc[2], i, 64);
    const float R10 = __shfl(bc[3], i, 64), R11 = __shfl(bc[4], i, 64), R12 = __shfl(bc[5], i, 64);
    const float R20 = __shfl(bc[6], i, 64), R21 = __shfl(bc[7], i, 64), R22 = __shfl(bc[8], i, 64);
    const float sc  = __shfl(bc[9], i, 64);
    const float Tx  = __shfl(bc[10], i, 64), Ty = __shfl(bc[11], i, 64), Tz = __shfl(bc[12], i, 64);
    const float s[12] = {S[i][0].x, S[i][0].y, S[i][0].z, S[i][0].w,
                         S[i][1].x, S[i][1].y, S[i][1].z, S[i][1].w,
                         S[i][2].x, S[i][2].y, S[i][2].z, S[i][2].w};
    const float d[12] = {D[i][0].x, D[i][0].y, D[i][0].z, D[i][0].w,
                         D[i][1].x, D[i][1].y, D[i][1].z, D[i][1].w,
                         D[i][2].x, D[i][2].y, D[i][2].z, D[i][2].w};
    float a = 0.0f;
#pragma unroll
    for (int q = 0; q < 4; ++q) {
      const float sx = s[3 * q + 0], sy = s[3 * q + 1], sz = s[3 * q + 2];
      const float dx = d[3 * q + 0], dy = d[3 * q + 1], dz = d[3 * q + 2];
      const float e0 = sc * (R00 * sx + R01 * sy + R02 * sz) + Tx - dx;
      const float e1 = sc * (R10 * sx + R11 * sy + R12 * sz) + Ty - dy;
      const float e2 = sc * (R20 * sx + R21 * sy + R22 * sz) + Tz - dz;
      a += fabsf(e0) + fabsf(e1) + fabsf(e2);
    }
    if (b0 + i < B) acc += a;  // mask clamped tail batches
  }
  acc = wredf(acc);
  if (lane == 0) partials[wid] = acc;
}

// ---------- Final reduce ----------
__global__ __launch_bounds__(1024) void geo_fin(const float* __restrict__ partials,
                                                float* __restrict__ out, int n,
                                                double inv_total) {
  const int t = threadIdx.x;
  double acc = 0.0;
  for (int i = t; i < n; i += 1024) acc += (double)partials[i];
#pragma unroll
  for (int off = 32; off; off >>= 1) acc += __shfl_xor(acc, off, 64);
  __shared__ double sred[16];
  if ((t & 63) == 0) sred[t >> 6] = acc;
  __syncthreads();
  if (t == 0) {
    double tot = 0.0;
#pragma unroll
    for (int k = 0; k < 16; ++k) tot += sred[k];
    out[0] = (float)(tot * inv_total);
  }
}

extern "C" void kernel_launch(void* const* d_in, const int* in_sizes, int n_in,
                              void* d_out, int out_size, void* d_ws, size_t ws_size,
                              hipStream_t stream) {
  const float* kp = (const float*)d_in[0];
  const int* perm = (const int*)d_in[1];
  float* out = (float*)d_out;
  const int B = in_sizes[1];
  const double inv_total = 1.0 / ((double)B * (double)GEO_N * 3.0);

  const int NW = (B + 3) / 4;      // one wave per 4 batches
  float* partials = (float*)d_ws;  // NW floats
  const int grid = (NW + 3) / 4;   // 4 waves per 256-thread block
  geo_wave4p<<<grid, 256, 0, stream>>>(kp, perm, partials, B, NW);
  geo_fin<<<1, 1024, 0, stream>>>(partials, out, NW, inv_total);
}

// Round 13
// 39.766 us; speedup vs baseline: 1.2060x; 1.0925x over previous
//
#include <hip/hip_runtime.h>
#include <math.h>

#define GEO_N 256

// Single-instruction HW approximations (~1 ulp) — validated r9-r12 (absmax 0.0).
__device__ __forceinline__ float frcp(float x) { return __builtin_amdgcn_rcpf(x); }
__device__ __forceinline__ float frsq(float x) { return __builtin_amdgcn_rsqf(x); }
__device__ __forceinline__ float fsqrtf_(float x) { return __builtin_amdgcn_sqrtf(x); }

__device__ __forceinline__ float wredf(float v) {
#pragma unroll
  for (int off = 32; off; off >>= 1) v += __shfl_xor(v, off, 64);
  return v;
}

// Null-space direction of (G - l*I) via max-norm cross product of rows.
__device__ __forceinline__ void eigvec3(float g00, float g01, float g02,
                                        float g11, float g12, float g22,
                                        float l, float v[3]) {
  const float m00 = g00 - l, m11 = g11 - l, m22 = g22 - l;
  // rows: (m00,g01,g02) (g01,m11,g12) (g02,g12,m22)
  const float a0 = g01 * g12 - g02 * m11, a1 = g02 * g01 - m00 * g12, a2 = m00 * m11 - g01 * g01;
  const float b0 = g01 * m22 - g02 * g12, b1 = g02 * g02 - m00 * m22, b2 = m00 * g12 - g01 * g02;
  const float c0 = m11 * m22 - g12 * g12, c1 = g12 * g02 - g01 * m22, c2 = g01 * g12 - m11 * g02;
  const float na = a0 * a0 + a1 * a1 + a2 * a2;
  const float nb = b0 * b0 + b1 * b1 + b2 * b2;
  const float nc = c0 * c0 + c1 * c1 + c2 * c2;
  float s0 = a0, s1 = a1, s2 = a2, ns = na;
  if (nb > ns) { s0 = b0; s1 = b1; s2 = b2; ns = nb; }
  if (nc > ns) { s0 = c0; s1 = c1; s2 = c2; ns = nc; }
  const bool bad = ns < 1e-28f;
  const float inv = frsq(fmaxf(ns, 1e-28f));
  v[0] = bad ? 1.0f : s0 * inv;
  v[1] = bad ? 0.0f : s1 * inv;
  v[2] = bad ? 0.0f : s2 * inv;
}

// From 16 raw moment sums -> R(9), scale, T(3) in bc[0..12].
// ANALYTIC closed-form: eigenvalues via characteristic-poly trisection
// (acos poly + short-Taylor cos), eigenvectors via cross-of-rows, v1 skipped
// via completeness, R = A * (V diag(1/sigma) V^T) = U V^T. Branchless, ~250
// VALU, ~150-cycle chain (vs Jacobi's ~600 VALU / ~2000-cycle serial chain).
__device__ __forceinline__ void solve_rst(const float s0in[16], float bc[13]) {
  const float invN = 1.0f / (float)GEO_N;
  const float smx = s0in[0] * invN, smy = s0in[1] * invN, smz = s0in[2] * invN;
  const float dmx = s0in[3] * invN, dmy = s0in[4] * invN, dmz = s0in[5] * invN;
  const float A00 = s0in[6] * invN - dmx * smx,  A01 = s0in[7] * invN - dmx * smy,  A02 = s0in[8] * invN - dmx * smz;
  const float A10 = s0in[9] * invN - dmy * smx,  A11 = s0in[10] * invN - dmy * smy, A12 = s0in[11] * invN - dmy * smz;
  const float A20 = s0in[12] * invN - dmz * smx, A21 = s0in[13] * invN - dmz * smy, A22 = s0in[14] * invN - dmz * smz;
  const float var_sum = s0in[15] * invN - (smx * smx + smy * smy + smz * smz);

  // G = A^T A (symmetric; G_ij = col_i . col_j)
  const float g00 = A00 * A00 + A10 * A10 + A20 * A20;
  const float g11 = A01 * A01 + A11 * A11 + A21 * A21;
  const float g22 = A02 * A02 + A12 * A12 + A22 * A22;
  const float g01 = A00 * A01 + A10 * A11 + A20 * A21;
  const float g02 = A00 * A02 + A10 * A12 + A20 * A22;
  const float g12 = A01 * A02 + A11 * A12 + A21 * A22;

  // Analytic eigenvalues (l0 >= l1 >= l2)
  const float q = (g00 + g11 + g22) * (1.0f / 3.0f);
  const float c00 = g00 - q, c11 = g11 - q, c22 = g22 - q;
  const float p1 = g01 * g01 + g02 * g02 + g12 * g12;
  const float p2 = c00 * c00 + c11 * c11 + c22 * c22 + 2.0f * p1;
  const float p = fsqrtf_(p2 * (1.0f / 6.0f));
  const float pinv = frcp(fmaxf(p, 1e-20f));
  const float detC = c00 * (c11 * c22 - g12 * g12)
                   - g01 * (g01 * c22 - g12 * g02)
                   + g02 * (g01 * g12 - c11 * g02);
  float rr = 0.5f * detC * pinv * pinv * pinv;
  rr = fminf(1.0f, fmaxf(-1.0f, rr));
  // acos via A&S 4.4.45 (|err| < 7e-5 rad)
  const float arr = fabsf(rr);
  const float acs = fsqrtf_(fmaxf(1.0f - arr, 0.0f)) *
      (1.5707288f + arr * (-0.2121144f + arr * (0.0742610f + arr * (-0.0187293f))));
  const float acr = (rr >= 0.0f) ? acs : (3.14159265f - acs);
  const float phi = acr * (1.0f / 3.0f);  // in [0, pi/3]
  // cos on [0, pi/3] via Taylor (err ~3e-5 at pi/3)
  const float x1 = phi * phi;
  const float cph = 1.0f + x1 * (-0.5f + x1 * ((1.0f / 24.0f) - x1 * (1.0f / 720.0f)));
  const float uu = 1.04719755f - phi;  // pi/3 - phi, in [0, pi/3]
  const float x2 = uu * uu;
  const float cp3 = -(1.0f + x2 * (-0.5f + x2 * ((1.0f / 24.0f) - x2 * (1.0f / 720.0f))));  // cos(phi+2pi/3)
  const float l0 = q + 2.0f * p * cph;
  const float l2 = q + 2.0f * p * cp3;
  const float l1 = 3.0f * q - l0 - l2;

  float v0[3], v2[3];
  eigvec3(g00, g01, g02, g11, g12, g22, l0, v0);
  eigvec3(g00, g01, g02, g11, g12, g22, l2, v2);

  const float sg0 = fsqrtf_(fmaxf(l0, 0.0f));
  const float sg1 = fsqrtf_(fmaxf(l1, 0.0f));
  const float sg2 = fsqrtf_(fmaxf(l2, 0.0f));
  const float iv0 = (sg0 > 1e-20f) ? frcp(sg0) : 0.0f;
  const float iv1 = (sg1 > 1e-20f) ? frcp(sg1) : 0.0f;
  const float iv2 = (sg2 > 1e-20f) ? frcp(sg2) : 0.0f;

  // W = V diag(1/sigma) V^T, with v1 v1^T = I - v0 v0^T - v2 v2^T
  const float da = iv0 - iv1, db = iv2 - iv1;
  const float w00 = iv1 + da * v0[0] * v0[0] + db * v2[0] * v2[0];
  const float w11 = iv1 + da * v0[1] * v0[1] + db * v2[1] * v2[1];
  const float w22 = iv1 + da * v0[2] * v0[2] + db * v2[2] * v2[2];
  const float w01 = da * v0[0] * v0[1] + db * v2[0] * v2[1];
  const float w02 = da * v0[0] * v0[2] + db * v2[0] * v2[2];
  const float w12 = da * v0[1] * v0[2] + db * v2[1] * v2[2];

  // R = A * W  (= U V^T, the orthogonal polar factor)
  const float R00 = A00 * w00 + A01 * w01 + A02 * w02;
  const float R01 = A00 * w01 + A01 * w11 + A02 * w12;
  const float R02 = A00 * w02 + A01 * w12 + A02 * w22;
  const float R10 = A10 * w00 + A11 * w01 + A12 * w02;
  const float R11 = A10 * w01 + A11 * w11 + A12 * w12;
  const float R12 = A10 * w02 + A11 * w12 + A12 * w22;
  const float R20 = A20 * w00 + A21 * w01 + A22 * w02;
  const float R21 = A20 * w01 + A21 * w11 + A22 * w12;
  const float R22 = A20 * w02 + A21 * w12 + A22 * w22;

  const float scale = (sg0 + sg1 + sg2) * frcp(fmaxf(var_sum, 1e-30f));
  bc[0] = R00; bc[1] = R01; bc[2] = R02;
  bc[3] = R10; bc[4] = R11; bc[5] = R12;
  bc[6] = R20; bc[7] = R21; bc[8] = R22;
  bc[9] = scale;
  bc[10] = dmx - scale * (R00 * smx + R01 * smy + R02 * smz);
  bc[11] = dmy - scale * (R10 * smx + R11 * smy + R12 * smz);
  bc[12] = dmz - scale * (R20 * smx + R21 * smy + R22 * smz);
}

// ---------- r12 structure (interleaved loads) + analytic solve. ----------
__global__ __launch_bounds__(256) void geo_wave4p(const float* __restrict__ kp,
                                                  const int* __restrict__ perm,
                                                  float* __restrict__ partials,
                                                  int B, int NW) {
  const int wid = (blockIdx.x << 2) | (threadIdx.x >> 6);
  if (wid >= NW) return;  // no barriers in this kernel -> early return safe
  const int lane = threadIdx.x & 63;
  const int b0 = wid * 4;
  const float4* base = (const float4*)kp;

  int pm[4];
#pragma unroll
  for (int i = 0; i < 4; ++i) pm[i] = perm[min(b0 + i, B - 1)];

  float4 S[4][3], D[4][3];
  float parked = 0.0f;

#define GEO_LOAD(i)                                                        \
  {                                                                        \
    const int bb = min(b0 + (i), B - 1);                                   \
    const float4* s4 = base + (size_t)bb * 192 + lane * 3;                 \
    const float4* d4 = base + (size_t)pm[(i)] * 192 + lane * 3;            \
    S[(i)][0] = s4[0]; S[(i)][1] = s4[1]; S[(i)][2] = s4[2];               \
    D[(i)][0] = d4[0]; D[(i)][1] = d4[1]; D[(i)][2] = d4[2];               \
  }

#define GEO_MOM(i)                                                         \
  {                                                                        \
    const float s_[12] = {S[(i)][0].x, S[(i)][0].y, S[(i)][0].z, S[(i)][0].w, \
                          S[(i)][1].x, S[(i)][1].y, S[(i)][1].z, S[(i)][1].w, \
                          S[(i)][2].x, S[(i)][2].y, S[(i)][2].z, S[(i)][2].w}; \
    const float d_[12] = {D[(i)][0].x, D[(i)][0].y, D[(i)][0].z, D[(i)][0].w, \
                          D[(i)][1].x, D[(i)][1].y, D[(i)][1].z, D[(i)][1].w, \
                          D[(i)][2].x, D[(i)][2].y, D[(i)][2].z, D[(i)][2].w}; \
    float r[16];                                                           \
    _Pragma("unroll") for (int k = 0; k < 16; ++k) r[k] = 0.0f;            \
    _Pragma("unroll") for (int p = 0; p < 4; ++p) {                        \
      const float sx = s_[3 * p + 0], sy = s_[3 * p + 1], sz = s_[3 * p + 2]; \
      const float dx = d_[3 * p + 0], dy = d_[3 * p + 1], dz = d_[3 * p + 2]; \
      r[0] += sx; r[1] += sy; r[2] += sz;                                  \
      r[3] += dx; r[4] += dy; r[5] += dz;                                  \
      r[6] += dx * sx; r[7] += dx * sy; r[8] += dx * sz;                   \
      r[9] += dy * sx; r[10] += dy * sy; r[11] += dy * sz;                 \
      r[12] += dz * sx; r[13] += dz * sy; r[14] += dz * sz;                \
      r[15] += sx * sx + sy * sy + sz * sz;                                \
    }                                                                      \
    const int b1 = lane & 1, b2 = (lane >> 1) & 1, b3 = (lane >> 2) & 1, b4 = (lane >> 3) & 1; \
    float v8[8], v4_[4], v2_[2], v1;                                       \
    _Pragma("unroll") for (int k = 0; k < 8; ++k) {                        \
      float send = b1 ? r[k] : r[k + 8];                                   \
      float recv = __shfl_xor(send, 1, 64);                                \
      v8[k] = (b1 ? r[k + 8] : r[k]) + recv;                               \
    }                                                                      \
    _Pragma("unroll") for (int k = 0; k < 4; ++k) {                        \
      float send = b2 ? v8[k] : v8[k + 4];                                 \
      float recv = __shfl_xor(send, 2, 64);                                \
      v4_[k] = (b2 ? v8[k + 4] : v8[k]) + recv;                            \
    }                                                                      \
    _Pragma("unroll") for (int k = 0; k < 2; ++k) {                        \
      float send = b3 ? v4_[k] : v4_[k + 2];                               \
      float recv = __shfl_xor(send, 4, 64);                                \
      v2_[k] = (b3 ? v4_[k + 2] : v4_[k]) + recv;                          \
    }                                                                      \
    {                                                                      \
      float send = b4 ? v2_[0] : v2_[1];                                   \
      float recv = __shfl_xor(send, 8, 64);                                \
      v1 = (b4 ? v2_[1] : v2_[0]) + recv;                                  \
    }                                                                      \
    v1 += __shfl_xor(v1, 16, 64);                                          \
    v1 += __shfl_xor(v1, 32, 64);                                          \
    if ((lane >> 4) == (i)) parked = v1;                                   \
  }

  // ---- Pipelined schedule: loads interleaved with compute ----
  GEO_LOAD(0)
  GEO_LOAD(1)
  __builtin_amdgcn_sched_barrier(0);
  GEO_MOM(0)
  GEO_LOAD(2)
  __builtin_amdgcn_sched_barrier(0);
  GEO_MOM(1)
  GEO_LOAD(3)
  __builtin_amdgcn_sched_barrier(0);
  GEO_MOM(2)
  __builtin_amdgcn_sched_barrier(0);
  GEO_MOM(3)

#undef GEO_LOAD
#undef GEO_MOM

  // ---- shfl-transpose: lane t gathers batch (t&3)'s 16 moments ----
  constexpr int br[16] = {0, 8, 4, 12, 2, 10, 6, 14, 1, 9, 5, 13, 3, 11, 7, 15};
  float s0[16];
#pragma unroll
  for (int k = 0; k < 16; ++k)
    s0[k] = __shfl(parked, ((lane & 3) << 4) | br[k], 64);

  // ---- One solve per wave (lane t solves batch b0 + (t&3)) ----
  float bc[13];
  solve_rst(s0, bc);

  // ---- Errors from live registers; params broadcast from lane i ----
  float acc = 0.0f;
#pragma unroll
  for (int i = 0; i < 4; ++i) {
    const float R00 = __shfl(bc[0], i, 64), R01 = __shfl(bc[1], i, 64), R02 = __shfl(bc[2], i, 64);
    const float R10 = __shfl(bc[3], i, 64), R11 = __shfl(bc[4], i, 64), R12 = __shfl(bc[5], i, 64);
    const float R20 = __shfl(bc[6], i, 64), R21 = __shfl(bc[7], i, 64), R22 = __shfl(bc[8], i, 64);
    const float sc  = __shfl(bc[9], i, 64);
    const float Tx  = __shfl(bc[10], i, 64), Ty = __shfl(bc[11], i, 64), Tz = __shfl(bc[12], i, 64);
    const float s[12] = {S[i][0].x, S[i][0].y, S[i][0].z, S[i][0].w,
                         S[i][1].x, S[i][1].y, S[i][1].z, S[i][1].w,
                         S[i][2].x, S[i][2].y, S[i][2].z, S[i][2].w};
    const float d[12] = {D[i][0].x, D[i][0].y, D[i][0].z, D[i][0].w,
                         D[i][1].x, D[i][1].y, D[i][1].z, D[i][1].w,
                         D[i][2].x, D[i][2].y, D[i][2].z, D[i][2].w};
    float a = 0.0f;
#pragma unroll
    for (int q = 0; q < 4; ++q) {
      const float sx = s[3 * q + 0], sy = s[3 * q + 1], sz = s[3 * q + 2];
      const float dx = d[3 * q + 0], dy = d[3 * q + 1], dz = d[3 * q + 2];
      const float e0 = sc * (R00 * sx + R01 * sy + R02 * sz) + Tx - dx;
      const float e1 = sc * (R10 * sx + R11 * sy + R12 * sz) + Ty - dy;
      const float e2 = sc * (R20 * sx + R21 * sy + R22 * sz) + Tz - dz;
      a += fabsf(e0) + fabsf(e1) + fabsf(e2);
    }
    if (b0 + i < B) acc += a;  // mask clamped tail batches
  }
  acc = wredf(acc);
  if (lane == 0) partials[wid] = acc;
}

// ---------- Final reduce ----------
__global__ __launch_bounds__(1024) void geo_fin(const float* __restrict__ partials,
                                                float* __restrict__ out, int n,
                                                double inv_total) {
  const int t = threadIdx.x;
  double acc = 0.0;
  for (int i = t; i < n; i += 1024) acc += (double)partials[i];
#pragma unroll
  for (int off = 32; off; off >>= 1) acc += __shfl_xor(acc, off, 64);
  __shared__ double sred[16];
  if ((t & 63) == 0) sred[t >> 6] = acc;
  __syncthreads();
  if (t == 0) {
    double tot = 0.0;
#pragma unroll
    for (int k = 0; k < 16; ++k) tot += sred[k];
    out[0] = (float)(tot * inv_total);
  }
}

extern "C" void kernel_launch(void* const* d_in, const int* in_sizes, int n_in,
                              void* d_out, int out_size, void* d_ws, size_t ws_size,
                              hipStream_t stream) {
  const float* kp = (const float*)d_in[0];
  const int* perm = (const int*)d_in[1];
  float* out = (float*)d_out;
  const int B = in_sizes[1];
  const double inv_total = 1.0 / ((double)B * (double)GEO_N * 3.0);

  const int NW = (B + 3) / 4;      // one wave per 4 batches
  float* partials = (float*)d_ws;  // NW floats
  const int grid = (NW + 3) / 4;   // 4 waves per 256-thread block
  geo_wave4p<<<grid, 256, 0, stream>>>(kp, perm, partials, B, NW);
  geo_fin<<<1, 1024, 0, stream>>>(partials, out, NW, inv_total);
}